// Round 1
// baseline (311.121 us; speedup 1.0000x reference)
//
#include <hip/hip_runtime.h>

#define NN 50000
#define NE 800000
#define D  64

// ---------------------------------------------------------------------------
// Phase 1: edge scatter. One 64-lane wave per edge (grid-stride over waves).
// lane j: aggF[dst][j] += feat[src][j]; lane 0: sW[dst] += w[e].
// ---------------------------------------------------------------------------
__global__ __launch_bounds__(256) void edge_scatter(
    const float* __restrict__ feat,
    const float* __restrict__ ew,
    const int*   __restrict__ src,
    const int*   __restrict__ dst,
    float* __restrict__ aggF,
    float* __restrict__ sW)
{
    const int lane   = threadIdx.x & 63;
    const int wave   = (blockIdx.x * blockDim.x + threadIdx.x) >> 6;
    const int nwaves = (gridDim.x * blockDim.x) >> 6;

    for (int e = wave; e < NE; e += nwaves) {
        const int s = src[e];
        const int d = dst[e];
        const float v = feat[s * D + lane];
        unsafeAtomicAdd(&aggF[d * D + lane], v);
        if (lane == 0) {
            unsafeAtomicAdd(&sW[d], ew[e]);
        }
    }
}

// ---------------------------------------------------------------------------
// Phase 2: out[i][j] = sum_k feat[i][k]*W1[k][j] + aggF[i][k]*W2[k][j]
//                      - sW[i]*colsum(W2)[j]
// One wave per row; W1/W2 staged in LDS; feat/agg row broadcast via __shfl.
// ---------------------------------------------------------------------------
__global__ __launch_bounds__(256) void finalize(
    const float* __restrict__ feat,
    const float* __restrict__ aggF,
    const float* __restrict__ sW,
    const float* __restrict__ W1,
    const float* __restrict__ W2,
    float* __restrict__ out)
{
    __shared__ float w1s[D * D];
    __shared__ float w2s[D * D];
    __shared__ float csum[D];

    const int tid = threadIdx.x;           // 256 threads = 4 waves
    for (int i = tid; i < D * D; i += 256) {
        w1s[i] = W1[i];
        w2s[i] = W2[i];
    }
    __syncthreads();
    if (tid < D) {
        float c = 0.f;
        for (int k = 0; k < D; ++k) c += w2s[k * D + tid];
        csum[tid] = c;
    }
    __syncthreads();

    const int lane   = tid & 63;
    const int wave   = (blockIdx.x * blockDim.x + tid) >> 6;
    const int nwaves = (gridDim.x * blockDim.x) >> 6;

    for (int row = wave; row < NN; row += nwaves) {
        const float f = feat[row * D + lane];
        const float a = aggF[row * D + lane];
        float acc = -sW[row] * csum[lane];
        #pragma unroll
        for (int k = 0; k < D; ++k) {
            const float fk = __shfl(f, k);
            const float ak = __shfl(a, k);
            acc += fk * w1s[k * D + lane] + ak * w2s[k * D + lane];
        }
        out[row * D + lane] = acc;
    }
}

// ---------------------------------------------------------------------------
extern "C" void kernel_launch(void* const* d_in, const int* in_sizes, int n_in,
                              void* d_out, int out_size, void* d_ws, size_t ws_size,
                              hipStream_t stream)
{
    const float* feat = (const float*)d_in[0];   // [NN, D]
    const float* ew   = (const float*)d_in[1];   // [NE, 1]
    const float* W1   = (const float*)d_in[2];   // [D, D]
    const float* W2   = (const float*)d_in[3];   // [D, D]
    const int*   src  = (const int*)  d_in[4];   // [NE]
    const int*   dst  = (const int*)  d_in[5];   // [NE]
    float* out = (float*)d_out;                  // [NN, D]

    float* aggF = (float*)d_ws;                                  // NN*D floats
    float* sW   = (float*)((char*)d_ws + (size_t)NN * D * 4);    // NN floats

    // zero accumulators (13.0 MB) — stream memset is graph-capture safe
    hipMemsetAsync(d_ws, 0, (size_t)NN * D * 4 + (size_t)NN * 4, stream);

    // Phase 1: 4096 blocks * 256 thr = 16384 waves, ~49 edges each
    edge_scatter<<<4096, 256, 0, stream>>>(feat, ew, src, dst, aggF, sW);

    // Phase 2: 2048 blocks * 4 waves = 8192 waves, ~6 rows each
    finalize<<<2048, 256, 0, stream>>>(feat, aggF, sW, W1, W2, out);
}

// Round 2
// 216.829 us; speedup vs baseline: 1.4349x; 1.4349x over previous
//
#include <hip/hip_runtime.h>

#define NN 50000
#define NE 800000
#define D  64
#define NPAD 50176          // 196 * 256, >= NN+1
#define NBLK_SCAN 196

// ---------------------------------------------------------------------------
// CSR build step 1: histogram of dst
// ---------------------------------------------------------------------------
__global__ __launch_bounds__(256) void hist_kernel(const int* __restrict__ dst,
                                                   int* __restrict__ cnt)
{
    int e = blockIdx.x * 256 + threadIdx.x;
    if (e < NE) atomicAdd(&cnt[dst[e]], 1);
}

// step 2a: per-block partial sums of cnt
__global__ __launch_bounds__(256) void scan_partials(const int* __restrict__ cnt,
                                                     int* __restrict__ bsum)
{
    __shared__ int ws[4];
    int i = blockIdx.x * 256 + threadIdx.x;
    int v = cnt[i];
    for (int off = 32; off; off >>= 1) v += __shfl_xor(v, off);
    int lane = threadIdx.x & 63, w = threadIdx.x >> 6;
    if (lane == 0) ws[w] = v;
    __syncthreads();
    if (threadIdx.x == 0) bsum[blockIdx.x] = ws[0] + ws[1] + ws[2] + ws[3];
}

// step 2b: exclusive scan of the 196 block sums (trivially serial)
__global__ void scan_bsums(int* bsum)
{
    if (threadIdx.x == 0 && blockIdx.x == 0) {
        int run = 0;
        for (int i = 0; i < NBLK_SCAN; ++i) { int t = bsum[i]; bsum[i] = run; run += t; }
    }
}

// step 2c: block-local exclusive scan + block offset -> start[], cursor[]
__global__ __launch_bounds__(256) void scan_final(const int* __restrict__ cnt,
                                                  const int* __restrict__ bsum,
                                                  int* __restrict__ start,
                                                  int* __restrict__ cursor)
{
    __shared__ int wtot[4];
    int i = blockIdx.x * 256 + threadIdx.x;
    int lane = threadIdx.x & 63, w = threadIdx.x >> 6;
    int v = cnt[i];
    int sc = v;
    for (int off = 1; off < 64; off <<= 1) {
        int x = __shfl_up(sc, off);
        if (lane >= off) sc += x;
    }
    if (lane == 63) wtot[w] = sc;
    __syncthreads();
    int woff = 0;
    #pragma unroll
    for (int k = 0; k < 4; ++k) if (k < w) woff += wtot[k];
    int excl = sc - v + woff + bsum[blockIdx.x];
    start[i] = excl;
    if (i < NN) cursor[i] = excl;
}

// step 3: scatter (src, w) into dst-sorted order
__global__ __launch_bounds__(256) void scatter_kernel(const int* __restrict__ src,
                                                      const int* __restrict__ dst,
                                                      const float* __restrict__ ew,
                                                      int* __restrict__ cursor,
                                                      int* __restrict__ ssrc,
                                                      float* __restrict__ swv)
{
    int e = blockIdx.x * 256 + threadIdx.x;
    if (e < NE) {
        int d = dst[e];
        int pos = atomicAdd(&cursor[d], 1);
        ssrc[pos] = src[e];
        swv[pos] = ew[e];
    }
}

// ---------------------------------------------------------------------------
// Aggregation as a gather: one wave per node, no fp atomics.
// agg[n][lane] = sum_{e in bucket(n)} feat[ssrc[e]][lane];  sW[n] = sum w
// ---------------------------------------------------------------------------
__global__ __launch_bounds__(256) void gather_kernel(const float* __restrict__ feat,
                                                     const int* __restrict__ start,
                                                     const int* __restrict__ ssrc,
                                                     const float* __restrict__ swv,
                                                     float* __restrict__ agg,
                                                     float* __restrict__ sWout)
{
    int wid = (blockIdx.x * 256 + threadIdx.x) >> 6;
    int lane = threadIdx.x & 63;
    if (wid >= NN) return;
    int beg = start[wid], end = start[wid + 1];

    float acc = 0.f;
    for (int e = beg; e < end; ++e) {
        int s = ssrc[e];                  // wave-uniform -> broadcast load
        acc += feat[s * D + lane];        // 256B coalesced row, L2/L3-resident
    }
    agg[wid * D + lane] = acc;

    float swa = 0.f;
    for (int e = beg + lane; e < end; e += 64) swa += swv[e];
    for (int off = 32; off; off >>= 1) swa += __shfl_xor(swa, off);
    if (lane == 0) sWout[wid] = swa;
}

// ---------------------------------------------------------------------------
// Epilogue GEMM: out = feat@W1 + agg@W2 - sW ⊗ colsum(W2)
// 64x64 tile per block, 4x4 outputs per thread, float4 LDS reads.
// ---------------------------------------------------------------------------
__global__ __launch_bounds__(256) void gemm_kernel(const float* __restrict__ feat,
                                                   const float* __restrict__ agg,
                                                   const float* __restrict__ sW,
                                                   const float* __restrict__ W1,
                                                   const float* __restrict__ W2,
                                                   float* __restrict__ out)
{
    __shared__ float As[64][68];   // stride 68 floats = 272B: 16B-aligned float4, <=2-way banks
    __shared__ float Bs[64][68];
    __shared__ float w1s[64 * 64];
    __shared__ float w2s[64 * 64];
    __shared__ float csum[64];
    __shared__ float swS[64];

    const int t = threadIdx.x;
    const int r0 = blockIdx.x * 64;

    for (int idx = t; idx < 64 * 64; idx += 256) {
        int r = idx >> 6, c = idx & 63;
        int gr = r0 + r;
        As[r][c] = (gr < NN) ? feat[gr * D + c] : 0.f;
        Bs[r][c] = (gr < NN) ? agg[gr * D + c] : 0.f;
        w1s[idx] = W1[idx];
        w2s[idx] = W2[idx];
    }
    if (t < 64) swS[t] = (r0 + t < NN) ? sW[r0 + t] : 0.f;
    __syncthreads();
    if (t < 64) {
        float c = 0.f;
        for (int k = 0; k < 64; ++k) c += w2s[k * 64 + t];
        csum[t] = c;
    }
    __syncthreads();

    const int cg = t & 15;         // col group: cols j0..j0+3
    const int rg = t >> 4;         // row group: rows rg*4..rg*4+3
    const int j0 = cg * 4;
    const float4* w1v = (const float4*)w1s;
    const float4* w2v = (const float4*)w2s;

    float acc[4][4] = {};

    #pragma unroll 4
    for (int k4 = 0; k4 < 16; ++k4) {
        float4 av[4];
        #pragma unroll
        for (int i = 0; i < 4; ++i) av[i] = *(const float4*)&As[rg * 4 + i][k4 * 4];
        #pragma unroll
        for (int kk = 0; kk < 4; ++kk) {
            float4 wv = w1v[(k4 * 4 + kk) * 16 + cg];
            #pragma unroll
            for (int i = 0; i < 4; ++i) {
                float a = (&av[i].x)[kk];
                acc[i][0] += a * wv.x; acc[i][1] += a * wv.y;
                acc[i][2] += a * wv.z; acc[i][3] += a * wv.w;
            }
        }
    }
    #pragma unroll 4
    for (int k4 = 0; k4 < 16; ++k4) {
        float4 av[4];
        #pragma unroll
        for (int i = 0; i < 4; ++i) av[i] = *(const float4*)&Bs[rg * 4 + i][k4 * 4];
        #pragma unroll
        for (int kk = 0; kk < 4; ++kk) {
            float4 wv = w2v[(k4 * 4 + kk) * 16 + cg];
            #pragma unroll
            for (int i = 0; i < 4; ++i) {
                float a = (&av[i].x)[kk];
                acc[i][0] += a * wv.x; acc[i][1] += a * wv.y;
                acc[i][2] += a * wv.z; acc[i][3] += a * wv.w;
            }
        }
    }

    #pragma unroll
    for (int i = 0; i < 4; ++i) {
        int r = rg * 4 + i, gr = r0 + r;
        if (gr < NN) {
            float s = swS[r];
            float4 o;
            o.x = acc[i][0] - s * csum[j0 + 0];
            o.y = acc[i][1] - s * csum[j0 + 1];
            o.z = acc[i][2] - s * csum[j0 + 2];
            o.w = acc[i][3] - s * csum[j0 + 3];
            *(float4*)&out[gr * D + j0] = o;
        }
    }
}

// ---------------------------------------------------------------------------
extern "C" void kernel_launch(void* const* d_in, const int* in_sizes, int n_in,
                              void* d_out, int out_size, void* d_ws, size_t ws_size,
                              hipStream_t stream)
{
    const float* feat = (const float*)d_in[0];
    const float* ew   = (const float*)d_in[1];
    const float* W1   = (const float*)d_in[2];
    const float* W2   = (const float*)d_in[3];
    const int*   src  = (const int*)  d_in[4];
    const int*   dst  = (const int*)  d_in[5];
    float* out = (float*)d_out;

    // workspace layout (256B-aligned chunks), ~20.0 MB total
    char* p = (char*)d_ws;
    size_t o = 0;
    auto take = [&](size_t bytes) { char* q = p + o; o = (o + bytes + 255) & ~(size_t)255; return q; };
    float* agg    = (float*)take((size_t)NN * D * 4);      // 12.8 MB
    int*   ssrc   = (int*)  take((size_t)NE * 4);          //  3.2 MB
    float* swv    = (float*)take((size_t)NE * 4);          //  3.2 MB
    int*   cnt    = (int*)  take((size_t)NPAD * 4);
    int*   start  = (int*)  take((size_t)NPAD * 4);
    int*   cursor = (int*)  take((size_t)NN * 4);
    int*   bsum   = (int*)  take((size_t)NBLK_SCAN * 4);
    float* sW     = (float*)take((size_t)NN * 4);

    hipMemsetAsync(cnt, 0, (size_t)NPAD * 4, stream);

    hist_kernel   <<<(NE + 255) / 256, 256, 0, stream>>>(dst, cnt);
    scan_partials <<<NBLK_SCAN, 256, 0, stream>>>(cnt, bsum);
    scan_bsums    <<<1, 64, 0, stream>>>(bsum);
    scan_final    <<<NBLK_SCAN, 256, 0, stream>>>(cnt, bsum, start, cursor);
    scatter_kernel<<<(NE + 255) / 256, 256, 0, stream>>>(src, dst, ew, cursor, ssrc, swv);

    gather_kernel <<<(NN * 64 + 255) / 256, 256, 0, stream>>>(feat, start, ssrc, swv, agg, sW);

    gemm_kernel   <<<(NN + 63) / 64, 256, 0, stream>>>(feat, agg, sW, W1, W2, out);
}

// Round 3
// 198.762 us; speedup vs baseline: 1.5653x; 1.0909x over previous
//
#include <hip/hip_runtime.h>

#define NN 50000
#define NE 800000
#define D  64
#define NPAD 50176          // 196 * 256, >= NN+1
#define NBLK_SCAN 196

// ---------------------------------------------------------------------------
// CSR build step 1: histogram of dst + fused per-node edge-weight sum
// ---------------------------------------------------------------------------
__global__ __launch_bounds__(256) void hist_kernel(const int* __restrict__ dst,
                                                   const float* __restrict__ ew,
                                                   int* __restrict__ cnt,
                                                   float* __restrict__ sW)
{
    int e = blockIdx.x * 256 + threadIdx.x;
    if (e < NE) {
        int d = dst[e];
        atomicAdd(&cnt[d], 1);
        unsafeAtomicAdd(&sW[d], ew[e]);
    }
}

// step 2a: per-block partial sums of cnt
__global__ __launch_bounds__(256) void scan_partials(const int* __restrict__ cnt,
                                                     int* __restrict__ bsum)
{
    __shared__ int ws[4];
    int i = blockIdx.x * 256 + threadIdx.x;
    int v = cnt[i];
    for (int off = 32; off; off >>= 1) v += __shfl_xor(v, off);
    int lane = threadIdx.x & 63, w = threadIdx.x >> 6;
    if (lane == 0) ws[w] = v;
    __syncthreads();
    if (threadIdx.x == 0) bsum[blockIdx.x] = ws[0] + ws[1] + ws[2] + ws[3];
}

// step 2b: exclusive scan of the 196 block sums
__global__ void scan_bsums(int* bsum)
{
    if (threadIdx.x == 0 && blockIdx.x == 0) {
        int run = 0;
        for (int i = 0; i < NBLK_SCAN; ++i) { int t = bsum[i]; bsum[i] = run; run += t; }
    }
}

// step 2c: block-local exclusive scan + block offset -> start[], cursor[]
__global__ __launch_bounds__(256) void scan_final(const int* __restrict__ cnt,
                                                  const int* __restrict__ bsum,
                                                  int* __restrict__ start,
                                                  int* __restrict__ cursor)
{
    __shared__ int wtot[4];
    int i = blockIdx.x * 256 + threadIdx.x;
    int lane = threadIdx.x & 63, w = threadIdx.x >> 6;
    int v = cnt[i];
    int sc = v;
    for (int off = 1; off < 64; off <<= 1) {
        int x = __shfl_up(sc, off);
        if (lane >= off) sc += x;
    }
    if (lane == 63) wtot[w] = sc;
    __syncthreads();
    int woff = 0;
    #pragma unroll
    for (int k = 0; k < 4; ++k) if (k < w) woff += wtot[k];
    int excl = sc - v + woff + bsum[blockIdx.x];
    start[i] = excl;
    if (i < NN) cursor[i] = excl;
}

// step 3: scatter src into dst-sorted order (4B per edge only)
__global__ __launch_bounds__(256) void scatter_kernel(const int* __restrict__ src,
                                                      const int* __restrict__ dst,
                                                      int* __restrict__ cursor,
                                                      int* __restrict__ ssrc)
{
    int e = blockIdx.x * 256 + threadIdx.x;
    if (e < NE) {
        int pos = atomicAdd(&cursor[dst[e]], 1);
        ssrc[pos] = src[e];
    }
}

// ---------------------------------------------------------------------------
// Aggregation gather: one wave per node, 4x16-lane groups, float4 rows,
// unroll x2 -> 8 independent feat-row loads in flight.
// ---------------------------------------------------------------------------
__global__ __launch_bounds__(256) void gather_kernel(const float* __restrict__ feat,
                                                     const int* __restrict__ start,
                                                     const int* __restrict__ ssrc,
                                                     float* __restrict__ agg)
{
    int wid = (blockIdx.x * 256 + threadIdx.x) >> 6;
    int lane = threadIdx.x & 63;
    if (wid >= NN) return;
    const int g  = lane >> 4;     // edge group 0..3
    const int li = lane & 15;     // float4 slot in row

    const int beg = start[wid], end = start[wid + 1];

    float4 acc = make_float4(0.f, 0.f, 0.f, 0.f);
    int e = beg + g;
    for (; e + 4 < end; e += 8) {
        int s0 = ssrc[e];
        int s1 = ssrc[e + 4];
        float4 v0 = *(const float4*)&feat[(size_t)s0 * D + li * 4];
        float4 v1 = *(const float4*)&feat[(size_t)s1 * D + li * 4];
        acc.x += v0.x + v1.x;
        acc.y += v0.y + v1.y;
        acc.z += v0.z + v1.z;
        acc.w += v0.w + v1.w;
    }
    if (e < end) {
        int s0 = ssrc[e];
        float4 v0 = *(const float4*)&feat[(size_t)s0 * D + li * 4];
        acc.x += v0.x; acc.y += v0.y; acc.z += v0.z; acc.w += v0.w;
    }

    // reduce across the 4 groups (lanes differing in bits 4,5)
    acc.x += __shfl_xor(acc.x, 16); acc.x += __shfl_xor(acc.x, 32);
    acc.y += __shfl_xor(acc.y, 16); acc.y += __shfl_xor(acc.y, 32);
    acc.z += __shfl_xor(acc.z, 16); acc.z += __shfl_xor(acc.z, 32);
    acc.w += __shfl_xor(acc.w, 16); acc.w += __shfl_xor(acc.w, 32);

    if (g == 0) {
        *(float4*)&agg[(size_t)wid * D + li * 4] = acc;
    }
}

// ---------------------------------------------------------------------------
// Epilogue GEMM: out = feat@W1 + agg@W2 - sW ⊗ colsum(W2)
// ---------------------------------------------------------------------------
__global__ __launch_bounds__(256) void gemm_kernel(const float* __restrict__ feat,
                                                   const float* __restrict__ agg,
                                                   const float* __restrict__ sW,
                                                   const float* __restrict__ W1,
                                                   const float* __restrict__ W2,
                                                   float* __restrict__ out)
{
    __shared__ float As[64][68];   // 68 floats = 17 float4 -> aligned, <=2-way banks
    __shared__ float Bs[64][68];
    __shared__ float w1s[64 * 64];
    __shared__ float w2s[64 * 64];
    __shared__ float csum[64];
    __shared__ float swS[64];

    const int t = threadIdx.x;
    const int r0 = blockIdx.x * 64;
    const float4 z4 = make_float4(0.f, 0.f, 0.f, 0.f);

    for (int idx = t; idx < 1024; idx += 256) {       // 64 rows x 16 float4
        int r = idx >> 4, c4 = idx & 15;
        int gr = r0 + r;
        float4 fv = z4, av = z4;
        if (gr < NN) {
            fv = *(const float4*)&feat[(size_t)gr * D + c4 * 4];
            av = *(const float4*)&agg [(size_t)gr * D + c4 * 4];
        }
        *(float4*)&As[r][c4 * 4] = fv;
        *(float4*)&Bs[r][c4 * 4] = av;
        ((float4*)w1s)[idx] = ((const float4*)W1)[idx];
        ((float4*)w2s)[idx] = ((const float4*)W2)[idx];
    }
    if (t < 64) swS[t] = (r0 + t < NN) ? sW[r0 + t] : 0.f;
    __syncthreads();
    if (t < 64) {
        float c = 0.f;
        for (int k = 0; k < 64; ++k) c += w2s[k * 64 + t];
        csum[t] = c;
    }
    __syncthreads();

    const int cg = t & 15;         // col group: cols j0..j0+3
    const int rg = t >> 4;         // row group: rows rg*4..rg*4+3
    const int j0 = cg * 4;
    const float4* w1v = (const float4*)w1s;
    const float4* w2v = (const float4*)w2s;

    float acc[4][4] = {};

    #pragma unroll 4
    for (int k4 = 0; k4 < 16; ++k4) {
        float4 av[4];
        #pragma unroll
        for (int i = 0; i < 4; ++i) av[i] = *(const float4*)&As[rg * 4 + i][k4 * 4];
        #pragma unroll
        for (int kk = 0; kk < 4; ++kk) {
            float4 wv = w1v[(k4 * 4 + kk) * 16 + cg];
            #pragma unroll
            for (int i = 0; i < 4; ++i) {
                float a = (&av[i].x)[kk];
                acc[i][0] += a * wv.x; acc[i][1] += a * wv.y;
                acc[i][2] += a * wv.z; acc[i][3] += a * wv.w;
            }
        }
    }
    #pragma unroll 4
    for (int k4 = 0; k4 < 16; ++k4) {
        float4 av[4];
        #pragma unroll
        for (int i = 0; i < 4; ++i) av[i] = *(const float4*)&Bs[rg * 4 + i][k4 * 4];
        #pragma unroll
        for (int kk = 0; kk < 4; ++kk) {
            float4 wv = w2v[(k4 * 4 + kk) * 16 + cg];
            #pragma unroll
            for (int i = 0; i < 4; ++i) {
                float a = (&av[i].x)[kk];
                acc[i][0] += a * wv.x; acc[i][1] += a * wv.y;
                acc[i][2] += a * wv.z; acc[i][3] += a * wv.w;
            }
        }
    }

    #pragma unroll
    for (int i = 0; i < 4; ++i) {
        int r = rg * 4 + i, gr = r0 + r;
        if (gr < NN) {
            float s = swS[r];
            float4 o;
            o.x = acc[i][0] - s * csum[j0 + 0];
            o.y = acc[i][1] - s * csum[j0 + 1];
            o.z = acc[i][2] - s * csum[j0 + 2];
            o.w = acc[i][3] - s * csum[j0 + 3];
            *(float4*)&out[(size_t)gr * D + j0] = o;
        }
    }
}

// ---------------------------------------------------------------------------
extern "C" void kernel_launch(void* const* d_in, const int* in_sizes, int n_in,
                              void* d_out, int out_size, void* d_ws, size_t ws_size,
                              hipStream_t stream)
{
    const float* feat = (const float*)d_in[0];
    const float* ew   = (const float*)d_in[1];
    const float* W1   = (const float*)d_in[2];
    const float* W2   = (const float*)d_in[3];
    const int*   src  = (const int*)  d_in[4];
    const int*   dst  = (const int*)  d_in[5];
    float* out = (float*)d_out;

    // workspace layout (256B-aligned chunks)
    char* p = (char*)d_ws;
    size_t o = 0;
    auto take = [&](size_t bytes) { char* q = p + o; o = (o + bytes + 255) & ~(size_t)255; return q; };
    float* agg    = (float*)take((size_t)NN * D * 4);      // 12.8 MB
    int*   ssrc   = (int*)  take((size_t)NE * 4);          //  3.2 MB
    int*   cnt    = (int*)  take((size_t)NPAD * 4);        // 200704 B (256-mult)
    float* sW     = (float*)take((size_t)NN * 4);          // contiguous after cnt
    int*   start  = (int*)  take((size_t)NPAD * 4);
    int*   cursor = (int*)  take((size_t)NN * 4);
    int*   bsum   = (int*)  take((size_t)NBLK_SCAN * 4);

    // zero cnt + sW in one memset (they are adjacent)
    hipMemsetAsync(cnt, 0, (size_t)NPAD * 4 + (size_t)NN * 4, stream);

    hist_kernel   <<<(NE + 255) / 256, 256, 0, stream>>>(dst, ew, cnt, sW);
    scan_partials <<<NBLK_SCAN, 256, 0, stream>>>(cnt, bsum);
    scan_bsums    <<<1, 64, 0, stream>>>(bsum);
    scan_final    <<<NBLK_SCAN, 256, 0, stream>>>(cnt, bsum, start, cursor);
    scatter_kernel<<<(NE + 255) / 256, 256, 0, stream>>>(src, dst, cursor, ssrc);

    gather_kernel <<<(NN * 64 + 255) / 256, 256, 0, stream>>>(feat, start, ssrc, agg);

    gemm_kernel   <<<(NN + 63) / 64, 256, 0, stream>>>(feat, agg, sW, W1, W2, out);
}

// Round 4
// 119.811 us; speedup vs baseline: 2.5968x; 1.6590x over previous
//
#include <hip/hip_runtime.h>

#define NN 50000
#define NE 800000
#define D  64
#define CAP 64                 // bucket capacity per node (max degree ~35 expected)
#define OFL_CAP 16384
#define WSCALE 16777216.0f     // 2^24 fixed point for edge-weight sums
#define INV_WSCALE (1.0f/16777216.0f)

// slots[d*8] (u64, padded to one 64B line per node):
//   hi32 = in-edge count, lo32 = sum of edge weights in 2^-24 fixed point.

// ---------------------------------------------------------------------------
// Single pass over edges: one padded u64 atomic gives count, weight-sum AND
// the within-bucket rank; scatter src directly to bucket[d][rank].
// ---------------------------------------------------------------------------
__global__ __launch_bounds__(256) void bin_kernel(
    const int* __restrict__ src, const int* __restrict__ dst,
    const float* __restrict__ ew,
    unsigned long long* __restrict__ slots,
    int* bucket,                       // [NN][CAP] — later aliased as agg
    int* __restrict__ ofl, int* __restrict__ oflCnt)
{
    int e = blockIdx.x * 256 + threadIdx.x;
    if (e >= NE) return;
    int d = dst[e];
    int s = src[e];
    unsigned int wfix = (unsigned int)(ew[e] * WSCALE + 0.5f);
    unsigned long long pack = (1ull << 32) | (unsigned long long)wfix;
    unsigned long long old = atomicAdd(&slots[(size_t)d * 8], pack);
    unsigned int r = (unsigned int)(old >> 32);
    if (r < CAP) {
        bucket[(size_t)d * CAP + r] = s;
    } else {
        int i = atomicAdd(oflCnt, 1);
        if (i < OFL_CAP) { ofl[2 * i] = d; ofl[2 * i + 1] = s; }
    }
}

// ---------------------------------------------------------------------------
// Gather: one wave per node; 4x16-lane groups each own an edge, float4 rows,
// unroll x2 -> 8 independent feat-row loads in flight. agg row overwrites the
// node's own bucket row (read-before-write within the wave).
// ---------------------------------------------------------------------------
__global__ __launch_bounds__(256) void gather_kernel(
    const float* __restrict__ feat,
    const unsigned long long* __restrict__ slots,
    void* bucket_agg)
{
    int wid = (blockIdx.x * 256 + threadIdx.x) >> 6;
    int lane = threadIdx.x & 63;
    if (wid >= NN) return;
    const int g  = lane >> 4;     // edge group 0..3
    const int li = lane & 15;     // float4 slot in row

    const int* bp = (const int*)bucket_agg + (size_t)wid * CAP;
    float* agg    = (float*)bucket_agg;

    unsigned long long sl = slots[(size_t)wid * 8];
    int n = (int)(sl >> 32);
    if (n > CAP) n = CAP;

    float4 acc = make_float4(0.f, 0.f, 0.f, 0.f);
    int e = g;
    for (; e + 4 < n; e += 8) {
        int s0 = bp[e];
        int s1 = bp[e + 4];
        float4 v0 = *(const float4*)&feat[(size_t)s0 * D + li * 4];
        float4 v1 = *(const float4*)&feat[(size_t)s1 * D + li * 4];
        acc.x += v0.x + v1.x;
        acc.y += v0.y + v1.y;
        acc.z += v0.z + v1.z;
        acc.w += v0.w + v1.w;
    }
    if (e < n) {
        int s0 = bp[e];
        float4 v0 = *(const float4*)&feat[(size_t)s0 * D + li * 4];
        acc.x += v0.x; acc.y += v0.y; acc.z += v0.z; acc.w += v0.w;
    }

    // reduce across the 4 groups (lane bits 4,5)
    acc.x += __shfl_xor(acc.x, 16); acc.x += __shfl_xor(acc.x, 32);
    acc.y += __shfl_xor(acc.y, 16); acc.y += __shfl_xor(acc.y, 32);
    acc.z += __shfl_xor(acc.z, 16); acc.z += __shfl_xor(acc.z, 32);
    acc.w += __shfl_xor(acc.w, 16); acc.w += __shfl_xor(acc.w, 32);

    if (g == 0) {
        *(float4*)&agg[(size_t)wid * D + li * 4] = acc;
    }
}

// ---------------------------------------------------------------------------
// Overflow fixup (expected empty): one wave per overflow edge, fp atomics.
// ---------------------------------------------------------------------------
__global__ __launch_bounds__(256) void ofl_kernel(
    const float* __restrict__ feat,
    const int* __restrict__ ofl, const int* __restrict__ oflCnt,
    float* agg)
{
    int n = *oflCnt;
    if (n > OFL_CAP) n = OFL_CAP;
    int w    = (blockIdx.x * 256 + threadIdx.x) >> 6;
    int lane = threadIdx.x & 63;
    int nw   = (gridDim.x * 256) >> 6;
    for (int i = w; i < n; i += nw) {
        int d = ofl[2 * i], s = ofl[2 * i + 1];
        unsafeAtomicAdd(&agg[(size_t)d * D + lane], feat[(size_t)s * D + lane]);
    }
}

// ---------------------------------------------------------------------------
// Epilogue GEMM: out = feat@W1 + agg@W2 - sW ⊗ colsum(W2)
// ---------------------------------------------------------------------------
__global__ __launch_bounds__(256) void gemm_kernel(
    const float* __restrict__ feat,
    const float* __restrict__ agg,
    const unsigned long long* __restrict__ slots,
    const float* __restrict__ W1,
    const float* __restrict__ W2,
    float* __restrict__ out)
{
    __shared__ float As[64][68];   // 68 floats = 17 float4: aligned, <=2-way banks
    __shared__ float Bs[64][68];
    __shared__ float w1s[64 * 64];
    __shared__ float w2s[64 * 64];
    __shared__ float csum[64];
    __shared__ float swS[64];

    const int t = threadIdx.x;
    const int r0 = blockIdx.x * 64;
    const float4 z4 = make_float4(0.f, 0.f, 0.f, 0.f);

    for (int idx = t; idx < 1024; idx += 256) {       // 64 rows x 16 float4
        int r = idx >> 4, c4 = idx & 15;
        int gr = r0 + r;
        float4 fv = z4, av = z4;
        if (gr < NN) {
            fv = *(const float4*)&feat[(size_t)gr * D + c4 * 4];
            av = *(const float4*)&agg [(size_t)gr * D + c4 * 4];
        }
        *(float4*)&As[r][c4 * 4] = fv;
        *(float4*)&Bs[r][c4 * 4] = av;
        ((float4*)w1s)[idx] = ((const float4*)W1)[idx];
        ((float4*)w2s)[idx] = ((const float4*)W2)[idx];
    }
    if (t < 64) {
        int gr = r0 + t;
        unsigned int wfix = (gr < NN)
            ? (unsigned int)(slots[(size_t)gr * 8] & 0xffffffffull) : 0u;
        swS[t] = (float)wfix * INV_WSCALE;
    }
    __syncthreads();
    if (t < 64) {
        float c = 0.f;
        for (int k = 0; k < 64; ++k) c += w2s[k * 64 + t];
        csum[t] = c;
    }
    __syncthreads();

    const int cg = t & 15;         // col group: cols j0..j0+3
    const int rg = t >> 4;         // row group: rows rg*4..rg*4+3
    const int j0 = cg * 4;
    const float4* w1v = (const float4*)w1s;
    const float4* w2v = (const float4*)w2s;

    float acc[4][4] = {};

    #pragma unroll 4
    for (int k4 = 0; k4 < 16; ++k4) {
        float4 av[4];
        #pragma unroll
        for (int i = 0; i < 4; ++i) av[i] = *(const float4*)&As[rg * 4 + i][k4 * 4];
        #pragma unroll
        for (int kk = 0; kk < 4; ++kk) {
            float4 wv = w1v[(k4 * 4 + kk) * 16 + cg];
            #pragma unroll
            for (int i = 0; i < 4; ++i) {
                float a = (&av[i].x)[kk];
                acc[i][0] += a * wv.x; acc[i][1] += a * wv.y;
                acc[i][2] += a * wv.z; acc[i][3] += a * wv.w;
            }
        }
    }
    #pragma unroll 4
    for (int k4 = 0; k4 < 16; ++k4) {
        float4 av[4];
        #pragma unroll
        for (int i = 0; i < 4; ++i) av[i] = *(const float4*)&Bs[rg * 4 + i][k4 * 4];
        #pragma unroll
        for (int kk = 0; kk < 4; ++kk) {
            float4 wv = w2v[(k4 * 4 + kk) * 16 + cg];
            #pragma unroll
            for (int i = 0; i < 4; ++i) {
                float a = (&av[i].x)[kk];
                acc[i][0] += a * wv.x; acc[i][1] += a * wv.y;
                acc[i][2] += a * wv.z; acc[i][3] += a * wv.w;
            }
        }
    }

    #pragma unroll
    for (int i = 0; i < 4; ++i) {
        int r = rg * 4 + i, gr = r0 + r;
        if (gr < NN) {
            float s = swS[r];
            float4 o;
            o.x = acc[i][0] - s * csum[j0 + 0];
            o.y = acc[i][1] - s * csum[j0 + 1];
            o.z = acc[i][2] - s * csum[j0 + 2];
            o.w = acc[i][3] - s * csum[j0 + 3];
            *(float4*)&out[(size_t)gr * D + j0] = o;
        }
    }
}

// ---------------------------------------------------------------------------
extern "C" void kernel_launch(void* const* d_in, const int* in_sizes, int n_in,
                              void* d_out, int out_size, void* d_ws, size_t ws_size,
                              hipStream_t stream)
{
    const float* feat = (const float*)d_in[0];
    const float* ew   = (const float*)d_in[1];
    const float* W1   = (const float*)d_in[2];
    const float* W2   = (const float*)d_in[3];
    const int*   src  = (const int*)  d_in[4];
    const int*   dst  = (const int*)  d_in[5];
    float* out = (float*)d_out;

    // workspace layout (~16.2 MB total)
    char* p = (char*)d_ws;
    unsigned long long* slots = (unsigned long long*)p;     // 50000 * 64B = 3,200,000
    int* oflCnt = (int*)(p + 3200000);                      // 256B region
    int* ofl    = (int*)(p + 3200256);                      // 16384 * 8B = 131,072
    float* aggF = (float*)(p + 3200256 + 131072);           // NN*CAP*4 = 12.8 MB (bucket/agg)

    // zero slots + overflow counter in one memset
    hipMemsetAsync(p, 0, 3200256, stream);

    bin_kernel   <<<(NE + 255) / 256, 256, 0, stream>>>(src, dst, ew, slots,
                                                        (int*)aggF, ofl, oflCnt);
    gather_kernel<<<(NN * 64 + 255) / 256, 256, 0, stream>>>(feat, slots, (void*)aggF);
    ofl_kernel   <<<32, 256, 0, stream>>>(feat, ofl, oflCnt, aggF);
    gemm_kernel  <<<(NN + 63) / 64, 256, 0, stream>>>(feat, aggF, slots, W1, W2, out);
}

// Round 5
// 83.078 us; speedup vs baseline: 3.7449x; 1.4422x over previous
//
#include <hip/hip_runtime.h>

#define NN 50000
#define NE 800000
#define D  64
#define NB 196            // bins of 256 nodes: bin = dst >> 8
#define EBLK 2048         // edges per K1/K3 block
#define NEB 391           // ceil(NE / EBLK)
#define K4CAP 2048        // LDS edge-staging cap per 64-node block (mean 1024)

typedef unsigned int u32;
typedef unsigned long long u64;

// record: [dst:16][src:16][w_bits:32]
__device__ __forceinline__ int wave_incl_scan(int v, int lane) {
    #pragma unroll
    for (int off = 1; off < 64; off <<= 1) {
        int t = __shfl_up(v, off);
        if (lane >= off) v += t;
    }
    return v;
}

// ---------------------------------------------------------------------------
// K1: per-block histogram over 196 bins (LDS atomics, coalesced global write)
// ---------------------------------------------------------------------------
__global__ __launch_bounds__(256) void k1_hist(const int* __restrict__ dst,
                                               u32* __restrict__ ghist)
{
    __shared__ u32 h[NB];
    int tid = threadIdx.x;
    if (tid < NB) h[tid] = 0;
    __syncthreads();
    int base = blockIdx.x * EBLK;
    int n = min(EBLK, NE - base);
    for (int k = tid; k < n; k += 256)
        atomicAdd(&h[((u32)dst[base + k]) >> 8], 1u);
    __syncthreads();
    if (tid < NB) ghist[blockIdx.x * NB + tid] = h[tid];
}

// ---------------------------------------------------------------------------
// K2: per-bin exclusive scan over the 391 block counts -> bbase[blk][bin],
// plus bin totals. One wave per bin.
// ---------------------------------------------------------------------------
__global__ __launch_bounds__(256) void k2_scan(const u32* __restrict__ ghist,
                                               u32* __restrict__ bbase,
                                               u32* __restrict__ binTot)
{
    int gw = (blockIdx.x * 256 + threadIdx.x) >> 6;
    int lane = threadIdx.x & 63;
    if (gw >= NB) return;
    u32 run = 0;
    for (int c = 0; c < 7; ++c) {              // 7*64 = 448 >= 391
        int blk = c * 64 + lane;
        u32 v = (blk < NEB) ? ghist[blk * NB + gw] : 0;
        int incl = wave_incl_scan((int)v, lane);
        if (blk < NEB) bbase[blk * NB + gw] = (u32)incl - v + run;
        run += (u32)__shfl(incl, 63);
    }
    if (lane == 0) binTot[gw] = run;
}

// K2b: exclusive scan of 196 bin totals -> binStart[0..196]
__global__ void k2b_scan(const u32* __restrict__ binTot, u32* __restrict__ binStart)
{
    int lane = threadIdx.x;
    if (lane < 64) {
        u32 carry = 0;
        for (int c = 0; c < 4; ++c) {
            int idx = c * 64 + lane;
            u32 v = (idx < NB) ? binTot[idx] : 0;
            int incl = wave_incl_scan((int)v, lane);
            if (idx <= NB) binStart[idx] = (u32)incl - v + carry;
            carry += (u32)__shfl(incl, 63);
        }
    }
}

// ---------------------------------------------------------------------------
// K3: stable-ish bin scatter with LDS reorder -> mostly-coalesced writes.
// ---------------------------------------------------------------------------
__global__ __launch_bounds__(256) void k3_scatter(const int* __restrict__ src,
                                                  const int* __restrict__ dst,
                                                  const float* __restrict__ ew,
                                                  const u32* __restrict__ bbase,
                                                  const u32* __restrict__ binStart,
                                                  u64* __restrict__ sorted)
{
    __shared__ u32 h[NB], eb[NB], ctr[NB], gb[NB];
    __shared__ u64 buf[EBLK];
    int tid = threadIdx.x;
    if (tid < NB) h[tid] = 0;
    __syncthreads();
    int base = blockIdx.x * EBLK;
    int n = min(EBLK, NE - base);
    for (int k = tid; k < n; k += 256)
        atomicAdd(&h[((u32)dst[base + k]) >> 8], 1u);
    __syncthreads();
    if (tid < 64) {
        u32 carry = 0;
        for (int c = 0; c < 4; ++c) {          // 4*64 = 256 >= 196
            int idx = c * 64 + tid;
            u32 v = (idx < NB) ? h[idx] : 0;
            int incl = wave_incl_scan((int)v, tid);
            if (idx < NB) { u32 e = (u32)incl - v + carry; eb[idx] = e; ctr[idx] = e; }
            carry += (u32)__shfl(incl, 63);
        }
    }
    if (tid < NB) gb[tid] = bbase[blockIdx.x * NB + tid] + binStart[tid];
    __syncthreads();
    for (int k = tid; k < n; k += 256) {
        int e = base + k;
        u32 d = (u32)dst[e], s = (u32)src[e];
        u64 rec = ((u64)((d << 16) | s) << 32) | (u64)__float_as_uint(ew[e]);
        u32 p = atomicAdd(&ctr[d >> 8], 1u);
        buf[p] = rec;
    }
    __syncthreads();
    for (int k = tid; k < n; k += 256) {
        u64 rec = buf[k];
        u32 bin = (u32)(rec >> 56);            // dst>>8
        sorted[gb[bin] + (u32)k - eb[bin]] = rec;
    }
}

// ---------------------------------------------------------------------------
// K4: fused per-node CSR build (in LDS) + register gather.
// Block owns 64 nodes (quarter of a bin); scans bin's contiguous records.
// ---------------------------------------------------------------------------
__global__ __launch_bounds__(256) void k4_gather(const float* __restrict__ feat,
                                                 const u64* __restrict__ sorted,
                                                 const u32* __restrict__ binStart,
                                                 float* __restrict__ agg,
                                                 float* __restrict__ sW)
{
    __shared__ u32 cnt[64], cbase[65], ctr[64];
    __shared__ u32 bs[K4CAP];
    __shared__ float bw[K4CAP];
    int tid = threadIdx.x;
    int nodeBase = blockIdx.x * 64;
    int bin = blockIdx.x >> 2;
    int beg = (int)binStart[bin], end = (int)binStart[bin + 1];

    if (tid < 64) cnt[tid] = 0;
    __syncthreads();
    for (int i = beg + tid; i < end; i += 256) {
        u64 rec = sorted[i];
        int ln = (int)(rec >> 48) - nodeBase;
        if (ln >= 0 && ln < 64) atomicAdd(&cnt[ln], 1u);
    }
    __syncthreads();
    if (tid < 64) {
        int incl = wave_incl_scan((int)cnt[tid], tid);
        u32 e = (u32)incl - cnt[tid];
        cbase[tid] = e; ctr[tid] = e;
        if (tid == 63) cbase[64] = (u32)incl;
    }
    __syncthreads();
    for (int i = beg + tid; i < end; i += 256) {
        u64 rec = sorted[i];
        int ln = (int)(rec >> 48) - nodeBase;
        if (ln >= 0 && ln < 64) {
            u32 p = atomicAdd(&ctr[ln], 1u);
            if (p < K4CAP) {
                bs[p] = (u32)(rec >> 32) & 0xffffu;
                bw[p] = __uint_as_float((u32)rec);
            }
        }
    }
    __syncthreads();

    int lane = tid & 63, w = tid >> 6;
    int g = lane >> 4, li = lane & 15;
    for (int t = 0; t < 16; ++t) {
        int ln = w * 16 + t;
        int node = nodeBase + ln;
        int b0 = min((int)cbase[ln], K4CAP);
        int b1 = min((int)cbase[ln + 1], K4CAP);
        float4 acc = make_float4(0.f, 0.f, 0.f, 0.f);
        float ws = 0.f;
        int e = b0 + g;
        for (; e + 4 < b1; e += 8) {
            int s0 = bs[e], s1 = bs[e + 4];
            ws += bw[e] + bw[e + 4];
            float4 v0 = *(const float4*)&feat[(size_t)s0 * D + li * 4];
            float4 v1 = *(const float4*)&feat[(size_t)s1 * D + li * 4];
            acc.x += v0.x + v1.x; acc.y += v0.y + v1.y;
            acc.z += v0.z + v1.z; acc.w += v0.w + v1.w;
        }
        if (e < b1) {
            int s0 = bs[e];
            ws += bw[e];
            float4 v0 = *(const float4*)&feat[(size_t)s0 * D + li * 4];
            acc.x += v0.x; acc.y += v0.y; acc.z += v0.z; acc.w += v0.w;
        }
        acc.x += __shfl_xor(acc.x, 16); acc.x += __shfl_xor(acc.x, 32);
        acc.y += __shfl_xor(acc.y, 16); acc.y += __shfl_xor(acc.y, 32);
        acc.z += __shfl_xor(acc.z, 16); acc.z += __shfl_xor(acc.z, 32);
        acc.w += __shfl_xor(acc.w, 16); acc.w += __shfl_xor(acc.w, 32);
        ws += __shfl_xor(ws, 16); ws += __shfl_xor(ws, 32);
        if (g == 0 && node < NN) {
            *(float4*)&agg[(size_t)node * D + li * 4] = acc;
            if (li == 0) sW[node] = ws;
        }
    }
}

// ---------------------------------------------------------------------------
// Epilogue GEMM: out = feat@W1 + agg@W2 - sW ⊗ colsum(W2)
// ---------------------------------------------------------------------------
__global__ __launch_bounds__(256) void gemm_kernel(
    const float* __restrict__ feat,
    const float* __restrict__ agg,
    const float* __restrict__ sW,
    const float* __restrict__ W1,
    const float* __restrict__ W2,
    float* __restrict__ out)
{
    __shared__ float As[64][68];
    __shared__ float Bs[64][68];
    __shared__ float w1s[64 * 64];
    __shared__ float w2s[64 * 64];
    __shared__ float csum[64];
    __shared__ float swS[64];

    const int t = threadIdx.x;
    const int r0 = blockIdx.x * 64;
    const float4 z4 = make_float4(0.f, 0.f, 0.f, 0.f);

    for (int idx = t; idx < 1024; idx += 256) {
        int r = idx >> 4, c4 = idx & 15;
        int gr = r0 + r;
        float4 fv = z4, av = z4;
        if (gr < NN) {
            fv = *(const float4*)&feat[(size_t)gr * D + c4 * 4];
            av = *(const float4*)&agg [(size_t)gr * D + c4 * 4];
        }
        *(float4*)&As[r][c4 * 4] = fv;
        *(float4*)&Bs[r][c4 * 4] = av;
        ((float4*)w1s)[idx] = ((const float4*)W1)[idx];
        ((float4*)w2s)[idx] = ((const float4*)W2)[idx];
    }
    if (t < 64) swS[t] = (r0 + t < NN) ? sW[r0 + t] : 0.f;
    __syncthreads();
    if (t < 64) {
        float c = 0.f;
        for (int k = 0; k < 64; ++k) c += w2s[k * 64 + t];
        csum[t] = c;
    }
    __syncthreads();

    const int cg = t & 15;
    const int rg = t >> 4;
    const int j0 = cg * 4;
    const float4* w1v = (const float4*)w1s;
    const float4* w2v = (const float4*)w2s;

    float acc[4][4] = {};

    #pragma unroll 4
    for (int k4 = 0; k4 < 16; ++k4) {
        float4 av[4];
        #pragma unroll
        for (int i = 0; i < 4; ++i) av[i] = *(const float4*)&As[rg * 4 + i][k4 * 4];
        #pragma unroll
        for (int kk = 0; kk < 4; ++kk) {
            float4 wv = w1v[(k4 * 4 + kk) * 16 + cg];
            #pragma unroll
            for (int i = 0; i < 4; ++i) {
                float a = (&av[i].x)[kk];
                acc[i][0] += a * wv.x; acc[i][1] += a * wv.y;
                acc[i][2] += a * wv.z; acc[i][3] += a * wv.w;
            }
        }
    }
    #pragma unroll 4
    for (int k4 = 0; k4 < 16; ++k4) {
        float4 av[4];
        #pragma unroll
        for (int i = 0; i < 4; ++i) av[i] = *(const float4*)&Bs[rg * 4 + i][k4 * 4];
        #pragma unroll
        for (int kk = 0; kk < 4; ++kk) {
            float4 wv = w2v[(k4 * 4 + kk) * 16 + cg];
            #pragma unroll
            for (int i = 0; i < 4; ++i) {
                float a = (&av[i].x)[kk];
                acc[i][0] += a * wv.x; acc[i][1] += a * wv.y;
                acc[i][2] += a * wv.z; acc[i][3] += a * wv.w;
            }
        }
    }

    #pragma unroll
    for (int i = 0; i < 4; ++i) {
        int r = rg * 4 + i, gr = r0 + r;
        if (gr < NN) {
            float s = swS[r];
            float4 o;
            o.x = acc[i][0] - s * csum[j0 + 0];
            o.y = acc[i][1] - s * csum[j0 + 1];
            o.z = acc[i][2] - s * csum[j0 + 2];
            o.w = acc[i][3] - s * csum[j0 + 3];
            *(float4*)&out[(size_t)gr * D + j0] = o;
        }
    }
}

// ---------------------------------------------------------------------------
extern "C" void kernel_launch(void* const* d_in, const int* in_sizes, int n_in,
                              void* d_out, int out_size, void* d_ws, size_t ws_size,
                              hipStream_t stream)
{
    const float* feat = (const float*)d_in[0];
    const float* ew   = (const float*)d_in[1];
    const float* W1   = (const float*)d_in[2];
    const float* W2   = (const float*)d_in[3];
    const int*   src  = (const int*)  d_in[4];
    const int*   dst  = (const int*)  d_in[5];
    float* out = (float*)d_out;

    // workspace layout (~20.0 MB; everything fully written before read -> no memset)
    char* p = (char*)d_ws;
    size_t o = 0;
    auto take = [&](size_t bytes) { char* q = p + o; o = (o + bytes + 255) & ~(size_t)255; return q; };
    u64* sorted   = (u64*)take((size_t)NE * 8);             // 6.4 MB
    u32* ghist    = (u32*)take((size_t)NEB * NB * 4);       // 306 KB
    u32* bbase    = (u32*)take((size_t)NEB * NB * 4);       // 306 KB
    u32* binTot   = (u32*)take((size_t)NB * 4);
    u32* binStart = (u32*)take((size_t)(NB + 1) * 4);
    float* agg    = (float*)take((size_t)NN * D * 4);       // 12.8 MB
    float* sW     = (float*)take((size_t)NN * 4);           // 200 KB

    k1_hist    <<<NEB, 256, 0, stream>>>(dst, ghist);
    k2_scan    <<<(NB * 64 + 255) / 256, 256, 0, stream>>>(ghist, bbase, binTot);
    k2b_scan   <<<1, 256, 0, stream>>>(binTot, binStart);
    k3_scatter <<<NEB, 256, 0, stream>>>(src, dst, ew, bbase, binStart, sorted);
    k4_gather  <<<(NN + 63) / 64, 256, 0, stream>>>(feat, sorted, binStart, agg, sW);
    gemm_kernel<<<(NN + 63) / 64, 256, 0, stream>>>(feat, agg, sW, W1, W2, out);
}